// Round 11
// baseline (113.371 us; speedup 1.0000x reference)
//
#include <hip/hip_runtime.h>
#include <hip/hip_bf16.h>

#define B_N 2048
#define D_V 8
#define F_D 256
#define TILE 128
#define LSTR 264   // np-kernel LDS stride (132 dw == 4 mod 32, conflict-free b128)

// sqrt(2*log2(e)) : zn scaled by this => MFMA acc = 2*log2(e)*dot => exp(2*dot) = exp2(acc)
#define SCALE_F 1.69864364f

#if defined(__has_builtin)
#  if __has_builtin(__builtin_amdgcn_exp2f)
#    define EXP2F(x) __builtin_amdgcn_exp2f(x)
#  else
#    define EXP2F(x) exp2f(x)
#  endif
#else
#  define EXP2F(x) exp2f(x)
#endif

typedef __attribute__((ext_vector_type(8))) short short8;
typedef __attribute__((ext_vector_type(4))) float floatx4;

__device__ inline unsigned short f2bf(float f) {
    __hip_bfloat16 h = __float2bfloat16(f);
    return *reinterpret_cast<unsigned short*>(&h);
}

__device__ inline float wave_reduce_sum(float v) {
    #pragma unroll
    for (int off = 1; off < 64; off <<= 1)
        v += __shfl_xor(v, off, 64);
    return v;
}

__device__ inline float wave_reduce_max(float v) {
    #pragma unroll
    for (int off = 1; off < 64; off <<= 1)
        v = fmaxf(v, __shfl_xor(v, off, 64));
    return v;
}

// ---------------------------------------------------------------------------
// Kernel 1: fused normalize + pos (R1/R7-verified). Block = 256 threads
// (4 waves) handles 4 samples (32 rows). Each wave normalizes its sample's
// 8 rows (writes scaled bf16 zn to global [d][b][f] AND LDS), then waves 0/1
// compute pos for 2 samples each via MFMA from LDS. Zero-inits ns8.
// ---------------------------------------------------------------------------
__global__ __launch_bounds__(256)
void np_kernel(const float* __restrict__ z, unsigned short* __restrict__ zn,
               float* __restrict__ ns8, float* __restrict__ pos) {
    __shared__ __align__(16) unsigned short Zs[32 * LSTR];  // 16.5 KB
    int tid = threadIdx.x;
    int gid = blockIdx.x * 256 + tid;
    if (gid < D_V * B_N) ns8[gid] = 0.0f;

    int w = tid >> 6, lane = tid & 63;
    int b = blockIdx.x * 4 + w;  // this wave's sample
    #pragma unroll
    for (int k = 0; k < 8; k++) {
        const float4 v = ((const float4*)(z + ((size_t)b * 8 + k) * F_D))[lane];
        float ss = v.x * v.x + v.y * v.y + v.z * v.z + v.w * v.w;
        ss = wave_reduce_sum(ss);
        float inv = SCALE_F / fmaxf(sqrtf(ss), 1e-12f);
        ushort4 o;
        o.x = f2bf(v.x * inv);
        o.y = f2bf(v.y * inv);
        o.z = f2bf(v.z * inv);
        o.w = f2bf(v.w * inv);
        ((ushort4*)(zn + (size_t)k * (B_N * F_D) + (size_t)b * F_D))[lane] = o;
        *(ushort4*)(&Zs[(w * 8 + k) * LSTR + lane * 4]) = o;
    }
    __syncthreads();

    // pos: wave 0 -> local samples 0,1 ; wave 1 -> local samples 2,3
    if (w < 2) {
        int q = lane >> 4, li = lane & 15;
        int lr = (w * 2 + (li >> 3)) * 8 + (li & 7);  // local row: sample*8 + view
        short8 a[8];
        #pragma unroll
        for (int kk = 0; kk < 8; kk++)
            a[kk] = *(const short8*)(&Zs[lr * LSTR + kk * 32 + q * 8]);
        floatx4 acc = {0.f, 0.f, 0.f, 0.f};
        #pragma unroll
        for (int kk = 0; kk < 8; kk++)
            acc = __builtin_amdgcn_mfma_f32_16x16x32_bf16(a[kk], a[kk], acc, 0, 0, 0);
        float p0 = 0.f, p1 = 0.f;
        #pragma unroll
        for (int r = 0; r < 4; r++) {
            int row = q * 4 + r, col = li;
            bool same_sample = (row >> 3) == (col >> 3);
            if (same_sample && row != col) {
                float e = EXP2F(acc[r]);   // acc already = 2*log2e*dot
                if (row < 8) p0 += e; else p1 += e;
            }
        }
        p0 = wave_reduce_sum(p0);
        p1 = wave_reduce_sum(p1);
        if (lane == 0) {
            int s0 = blockIdx.x * 4 + w * 2;
            pos[s0] = p0;
            pos[s0 + 1] = p1;
        }
    }
}

// ---------------------------------------------------------------------------
// Kernel 2 (symmetric-halved, LDS-FREE): per view d, upper-triangle 128x128
// tiles of S = exp(2 * Z Z^T): row-sums -> ns8[d][rows]; off-diag tiles also
// col-sums -> ns8[d][cols] (mirrored tile).
// Round-11: direct-L2 streaming (R3 idea with R3's defects removed).
// R7/R9/R10 ablation: LDS-traffic x2, barrier size, occupancy, block count
// all changed nothing -> the staged global->reg->LDS->reg chain itself is
// the invariant cost. Here: ONE WAVE per block (64 thr), 32 A-rows/wave
// (a[2][8]=64 VGPR), B-frags read straight from XCD-local L2 (plane = 1 MB,
// resident; d=bid&7 pin), each bf reused for 2 MFMAs. Zero LDS, zero
// barriers, 4352 fully independent waves; compiler pipelines ct+1 loads
// under ct MFMA+exp freely. Live ~140 VGPR; launch_bounds(64,3) caps at
// ~170 (headroom, not an R8-style squeeze -> no spill; tripwire: WRITE_SIZE
// must stay ~2.5 MB). L2-traffic floor: 4352 x 72 KB = 300 MB @ 34.5 TB/s
// ~ 9 us; vs staged path's realized ~29 us.
// ---------------------------------------------------------------------------
__global__ __launch_bounds__(64, 3)
void neg_kernel(const unsigned short* __restrict__ zn,
                float* __restrict__ ns8) {
    const int bid = blockIdx.x;
    const int d = bid & 7;            // view == XCD (perf heuristic; FETCH 10.4
                                      // vs 38.7 MB measured, R1 vs R2)
    int rest = bid >> 3;
    const int sub = rest & 3;         // which 32-row strip of the tile
    int trem = rest >> 2;             // 0..135 -> (i,j), i<=j
    int i = 0;
    while (trem >= 16 - i) { trem -= 16 - i; ++i; }
    const int j = i + trem;
    const bool diag = (i == j);
    const unsigned short* Z = zn + (size_t)d * (B_N * F_D);
    int lane = threadIdx.x & 63;
    int q = lane >> 4, li = lane & 15;
    const int r0 = i * TILE + sub * 32;   // this wave's 32 A-rows
    const int jc = j * TILE;

    // A-frags: 64 VGPR resident whole kernel (32 rows = 2 row-sets, K=256)
    short8 a[2][8];
    #pragma unroll
    for (int s = 0; s < 2; s++)
        #pragma unroll
        for (int kk = 0; kk < 8; kk++)
            a[s][kk] = *(const short8*)(Z + (size_t)(r0 + s * 16 + li) * F_D + kk * 32 + q * 8);

    float rs[2][4];
    #pragma unroll
    for (int s = 0; s < 2; s++)
        #pragma unroll
        for (int r = 0; r < 4; r++) rs[s][r] = 0.f;
    float cs[8];

    #pragma unroll
    for (int ct = 0; ct < 8; ++ct) {
        // B-frags for cols jc + ct*16 .. +15, straight from L2 (no LDS trip).
        // Per kk: 16 rows x 64 B = 16 full cache lines, coalesced.
        const unsigned short* bp = Z + (size_t)(jc + ct * 16 + li) * F_D + q * 8;
        short8 bf[8];
        #pragma unroll
        for (int kk = 0; kk < 8; kk++)
            bf[kk] = *(const short8*)(bp + kk * 32);
        floatx4 acc[2];
        acc[0] = (floatx4){0.f, 0.f, 0.f, 0.f};
        acc[1] = (floatx4){0.f, 0.f, 0.f, 0.f};
        #pragma unroll
        for (int kk = 0; kk < 8; kk++) {
            acc[0] = __builtin_amdgcn_mfma_f32_16x16x32_bf16(a[0][kk], bf[kk], acc[0], 0, 0, 0);
            acc[1] = __builtin_amdgcn_mfma_f32_16x16x32_bf16(a[1][kk], bf[kk], acc[1], 0, 0, 0);
        }
        // C/D layout: col = li, row(within 16-set) = q*4 + r
        int gcol = jc + ct * 16 + li;
        float csum = 0.f;
        #pragma unroll
        for (int s = 0; s < 2; s++) {
            #pragma unroll
            for (int r = 0; r < 4; r++) {
                float e = EXP2F(acc[s][r]);            // exp(2*dot), 1 trans op
                if (diag) {                            // uniform: 16/136 tiles
                    int grow = r0 + s * 16 + q * 4 + r;
                    if (grow == gcol) e = 0.f;
                }
                rs[s][r] += e;
                csum += e;
            }
        }
        // col partial over this wave's 32 rows: reduce across q-groups
        csum += __shfl_xor(csum, 16, 64);
        csum += __shfl_xor(csum, 32, 64);
        cs[ct] = csum;                                 // static index
    }

    // row sums: reduce across the 16 column-lanes; lanes li<8 own one (s,r)
    #pragma unroll
    for (int off = 1; off < 16; off <<= 1)
        #pragma unroll
        for (int s = 0; s < 2; s++)
            #pragma unroll
            for (int r = 0; r < 4; r++)
                rs[s][r] += __shfl_xor(rs[s][r], off, 64);
    {
        float rv = 0.f;
        #pragma unroll
        for (int s = 0; s < 2; s++)
            #pragma unroll
            for (int r = 0; r < 4; r++)
                if (li == s * 4 + r) rv = rs[s][r];
        if (li < 8)
            atomicAdd(&ns8[d * B_N + r0 + (li >> 2) * 16 + q * 4 + (li & 3)], rv);
    }

    // col sums (mirrored tile coverage): lane (q,li) owns cols q*16+li and
    // 64+q*16+li; each of the 4 strip-waves atomics its 32-row partial
    if (!diag) {
        float v0 = 0.f, v1 = 0.f;
        #pragma unroll
        for (int c = 0; c < 4; c++)
            if (q == c) { v0 = cs[c]; v1 = cs[c + 4]; }
        atomicAdd(&ns8[d * B_N + jc + q * 16 + li], v0);
        atomicAdd(&ns8[d * B_N + jc + 64 + q * 16 + li], v1);
    }
}

// ---------------------------------------------------------------------------
// Kernel 3: neg[b] = sum_d ns8[d][b] / (B-1); logits = pos/(pos+neg);
// loss = max + log(sum exp(l-max)) - mean(l). Shuffle-based reductions
// (verified R8/R9/R10).
// ---------------------------------------------------------------------------
__global__ void final_kernel(const float* __restrict__ pos,
                             const float* __restrict__ ns8,
                             float* __restrict__ out) {
    __shared__ float redm[4], reds[4], redl[4];
    int t = threadIdx.x, w = t >> 6, lane = t & 63;
    float vals[8];
    float lmax = -1e30f;
    #pragma unroll
    for (int i = 0; i < 8; i++) {
        int idx = t * 8 + i;
        float nsum = 0.f;
        #pragma unroll
        for (int d = 0; d < D_V; d++) nsum += ns8[d * B_N + idx];
        float p = pos[idx];
        float l = p / (p + nsum * (1.0f / (float)(B_N - 1)));
        vals[i] = l;
        lmax = fmaxf(lmax, l);
    }
    lmax = wave_reduce_max(lmax);
    if (lane == 0) redm[w] = lmax;
    __syncthreads();
    float m = fmaxf(fmaxf(redm[0], redm[1]), fmaxf(redm[2], redm[3]));
    float se = 0.f, sl = 0.f;
    #pragma unroll
    for (int i = 0; i < 8; i++) { se += expf(vals[i] - m); sl += vals[i]; }
    se = wave_reduce_sum(se);
    sl = wave_reduce_sum(sl);
    if (lane == 0) { reds[w] = se; redl[w] = sl; }
    __syncthreads();
    if (t == 0) {
        float S = reds[0] + reds[1] + reds[2] + reds[3];
        float L = redl[0] + redl[1] + redl[2] + redl[3];
        out[0] = m + logf(S) - L * (1.0f / (float)B_N);
    }
}

extern "C" void kernel_launch(void* const* d_in, const int* in_sizes, int n_in,
                              void* d_out, int out_size, void* d_ws, size_t ws_size,
                              hipStream_t stream) {
    const float* z = (const float*)d_in[0];
    float* out = (float*)d_out;
    unsigned short* zn = (unsigned short*)d_ws;                        // 8 MB bf16 (pre-scaled)
    float* ns8 = (float*)((char*)d_ws + (size_t)D_V * B_N * F_D * 2);  // 64 KB
    float* pos = ns8 + D_V * B_N;                                      // 8 KB

    np_kernel<<<dim3(512), 256, 0, stream>>>(z, zn, ns8, pos);
    neg_kernel<<<dim3(136 * 4 * 8), 64, 0, stream>>>(zn, ns8);
    final_kernel<<<1, 256, 0, stream>>>(pos, ns8, out);
}

// Round 12
// 86.015 us; speedup vs baseline: 1.3180x; 1.3180x over previous
//
#include <hip/hip_runtime.h>
#include <hip/hip_bf16.h>

#define B_N 2048
#define D_V 8
#define F_D 256
#define TILE 128
#define BC 64
#define LSTR 264   // 132 dwords == 4 (mod 32). For ds_*_b128, waves are serviced in
                   // 8-lane phases; lane li's 4-dword window starts at bank 4*li+c ->
                   // windows {0,4,...,28} tile all 32 banks: conflict-free.
                   // (557K at 264 = benign 2-way sub-phase aliasing, free per m136.
                   // 258 (==1): real 4-way, 1.67M, R2. 266 (==5): 2.79M, R5.)

// sqrt(2*log2(e)) : zn scaled by this => MFMA acc = 2*log2(e)*dot => exp(2*dot) = exp2(acc)
#define SCALE_F 1.69864364f

#if defined(__has_builtin)
#  if __has_builtin(__builtin_amdgcn_exp2f)
#    define EXP2F(x) __builtin_amdgcn_exp2f(x)
#  else
#    define EXP2F(x) exp2f(x)
#  endif
#else
#  define EXP2F(x) exp2f(x)
#endif

typedef __attribute__((ext_vector_type(8))) short short8;
typedef __attribute__((ext_vector_type(4))) float floatx4;

__device__ inline unsigned short f2bf(float f) {
    __hip_bfloat16 h = __float2bfloat16(f);
    return *reinterpret_cast<unsigned short*>(&h);
}

__device__ inline float wave_reduce_sum(float v) {
    #pragma unroll
    for (int off = 1; off < 64; off <<= 1)
        v += __shfl_xor(v, off, 64);
    return v;
}

__device__ inline float wave_reduce_max(float v) {
    #pragma unroll
    for (int off = 1; off < 64; off <<= 1)
        v = fmaxf(v, __shfl_xor(v, off, 64));
    return v;
}

// ---------------------------------------------------------------------------
// Kernel 1: fused normalize + pos (R7-verified, 86.3 us config). Block = 256
// threads (4 waves) handles 4 samples (32 rows). Each wave normalizes its
// sample's 8 rows (writes scaled bf16 zn to global [d][b][f] AND LDS), then
// waves 0/1 compute pos for 2 samples each via MFMA from LDS. Zero-inits ns8.
// ---------------------------------------------------------------------------
__global__ __launch_bounds__(256)
void np_kernel(const float* __restrict__ z, unsigned short* __restrict__ zn,
               float* __restrict__ ns8, float* __restrict__ pos) {
    __shared__ __align__(16) unsigned short Zs[32 * LSTR];  // 16.5 KB
    int tid = threadIdx.x;
    int gid = blockIdx.x * 256 + tid;
    if (gid < D_V * B_N) ns8[gid] = 0.0f;

    int w = tid >> 6, lane = tid & 63;
    int b = blockIdx.x * 4 + w;  // this wave's sample
    #pragma unroll
    for (int k = 0; k < 8; k++) {
        const float4 v = ((const float4*)(z + ((size_t)b * 8 + k) * F_D))[lane];
        float ss = v.x * v.x + v.y * v.y + v.z * v.z + v.w * v.w;
        ss = wave_reduce_sum(ss);
        float inv = SCALE_F / fmaxf(sqrtf(ss), 1e-12f);
        ushort4 o;
        o.x = f2bf(v.x * inv);
        o.y = f2bf(v.y * inv);
        o.z = f2bf(v.z * inv);
        o.w = f2bf(v.w * inv);
        ((ushort4*)(zn + (size_t)k * (B_N * F_D) + (size_t)b * F_D))[lane] = o;
        *(ushort4*)(&Zs[(w * 8 + k) * LSTR + lane * 4]) = o;
    }
    __syncthreads();

    // pos: wave 0 -> local samples 0,1 ; wave 1 -> local samples 2,3
    if (w < 2) {
        int q = lane >> 4, li = lane & 15;
        int lr = (w * 2 + (li >> 3)) * 8 + (li & 7);  // local row: sample*8 + view
        short8 a[8];
        #pragma unroll
        for (int kk = 0; kk < 8; kk++)
            a[kk] = *(const short8*)(&Zs[lr * LSTR + kk * 32 + q * 8]);
        floatx4 acc = {0.f, 0.f, 0.f, 0.f};
        #pragma unroll
        for (int kk = 0; kk < 8; kk++)
            acc = __builtin_amdgcn_mfma_f32_16x16x32_bf16(a[kk], a[kk], acc, 0, 0, 0);
        float p0 = 0.f, p1 = 0.f;
        #pragma unroll
        for (int r = 0; r < 4; r++) {
            int row = q * 4 + r, col = li;
            bool same_sample = (row >> 3) == (col >> 3);
            if (same_sample && row != col) {
                float e = EXP2F(acc[r]);   // acc already = 2*log2e*dot
                if (row < 8) p0 += e; else p1 += e;
            }
        }
        p0 = wave_reduce_sum(p0);
        p1 = wave_reduce_sum(p1);
        if (lane == 0) {
            int s0 = blockIdx.x * 4 + w * 2;
            pos[s0] = p0;
            pos[s0 + 1] = p1;
        }
    }
}

// One ct-sweep over the 64 staged B-columns currently in Bs.
// Uses: a, rs, cs, diag, r0, q, li; C0 = global col base, CSB = cs index base.
#define CT_SWEEP(C0, CSB)                                                        \
    do {                                                                         \
        _Pragma("unroll")                                                        \
        for (int ct = 0; ct < 4; ++ct) {                                         \
            const unsigned short* bp = &Bs[(ct * 16 + li) * LSTR + q * 8];       \
            floatx4 acc[2];                                                      \
            acc[0] = (floatx4){0.f, 0.f, 0.f, 0.f};                              \
            acc[1] = (floatx4){0.f, 0.f, 0.f, 0.f};                              \
            _Pragma("unroll")                                                    \
            for (int kk = 0; kk < 8; kk++) {                                     \
                short8 bf = *(const short8*)(bp + kk * 32);                      \
                acc[0] = __builtin_amdgcn_mfma_f32_16x16x32_bf16(a[0][kk], bf, acc[0], 0, 0, 0); \
                acc[1] = __builtin_amdgcn_mfma_f32_16x16x32_bf16(a[1][kk], bf, acc[1], 0, 0, 0); \
            }                                                                    \
            int gcol = (C0) + ct * 16 + li;                                      \
            float csum = 0.f;                                                    \
            _Pragma("unroll")                                                    \
            for (int s = 0; s < 2; s++) {                                        \
                _Pragma("unroll")                                                \
                for (int r = 0; r < 4; r++) {                                    \
                    float e = EXP2F(acc[s][r]);                                  \
                    if (diag) {                                                  \
                        int grow = r0 + s * 16 + q * 4 + r;                      \
                        if (grow == gcol) e = 0.f;                               \
                    }                                                            \
                    rs[s][r] += e;                                               \
                    csum += e;                                                   \
                }                                                                \
            }                                                                    \
            cs[(CSB) + ct] = csum;                                               \
        }                                                                        \
    } while (0)

// ---------------------------------------------------------------------------
// Kernel 2 (symmetric-halved): per view d, upper-triangle 128x128 tiles of
// S = exp(2 * Z Z^T): row-sums -> ns8[d][i*128+..]; off-diag tiles also
// col-sums -> ns8[d][j*128+..] (mirrored tile).
// R7-EXACT (best measured: 86.3 us total; structures R9/R10/R11 all equal or
// worse): 256 threads (4 waves x 32 A-rows); B staged in LDS 64 cols/stage;
// T14 async-stage split: both stages' loads issued up front to regs, stage-1
// ds_write after stage-0 compute barrier -> one exposed global latency.
// 1-D grid d=bid&7 XCD-pins each view's 1 MB plane (FETCH 10.4 vs 38.7 MB).
// ---------------------------------------------------------------------------
__global__ __launch_bounds__(256, 2)
void neg_kernel(const unsigned short* __restrict__ zn,
                float* __restrict__ ns8) {
    __shared__ __align__(16) unsigned short Bs[BC * LSTR];  // 33 KB
    const int bid = blockIdx.x;
    const int d = bid & 7;            // view == XCD (perf heuristic)
    int trem = bid >> 3;              // 0..135 -> (i,j), i<=j
    int i = 0;
    while (trem >= 16 - i) { trem -= 16 - i; ++i; }
    const int j = i + trem;
    const bool diag = (i == j);
    const unsigned short* Z = zn + (size_t)d * (B_N * F_D);
    int tid = threadIdx.x, w = tid >> 6, lane = tid & 63;
    int q = lane >> 4, li = lane & 15;
    int r0 = i * TILE + w * 32;       // this wave's 32 A-rows

    // A-frags: issued first, 64 VGPR resident whole kernel
    short8 a[2][8];
    #pragma unroll
    for (int s = 0; s < 2; s++)
        #pragma unroll
        for (int kk = 0; kk < 8; kk++)
            a[s][kk] = *(const short8*)(Z + (size_t)(r0 + s * 16 + li) * F_D + kk * 32 + q * 8);

    // B staging: thread covers 8 chunks; chunk it -> (row, kc)
    short8 breg[8];
    // stage-0 loads (in flight with A-loads)
    #pragma unroll
    for (int it = 0; it < 8; ++it) {
        int idx = it * 256 + tid;
        int row = idx >> 5, kc = idx & 31;
        breg[it] = *(const short8*)(Z + (size_t)(j * TILE + row) * F_D + kc * 8);
    }
    // write stage-0 to LDS (waits on stage-0 vmcnt: the one exposed latency)
    #pragma unroll
    for (int it = 0; it < 8; ++it) {
        int idx = it * 256 + tid;
        int row = idx >> 5, kc = idx & 31;
        *(short8*)(&Bs[row * LSTR + kc * 8]) = breg[it];
    }
    // stage-1 loads: issue NOW; they arrive during stage-0 compute
    #pragma unroll
    for (int it = 0; it < 8; ++it) {
        int idx = it * 256 + tid;
        int row = idx >> 5, kc = idx & 31;
        breg[it] = *(const short8*)(Z + (size_t)(j * TILE + BC + row) * F_D + kc * 8);
    }

    float rs[2][4];
    #pragma unroll
    for (int s = 0; s < 2; s++)
        #pragma unroll
        for (int r = 0; r < 4; r++) rs[s][r] = 0.f;
    float cs[8];

    __syncthreads();
    CT_SWEEP(j * TILE, 0);            // stage-0 compute (B1 loads in flight)
    __syncthreads();
    // stage-1 ds_write (breg long since arrived)
    #pragma unroll
    for (int it = 0; it < 8; ++it) {
        int idx = it * 256 + tid;
        int row = idx >> 5, kc = idx & 31;
        *(short8*)(&Bs[row * LSTR + kc * 8]) = breg[it];
    }
    __syncthreads();
    CT_SWEEP(j * TILE + BC, 4);       // stage-1 compute

    // row sums: reduce across the 16 column-lanes; lanes li<8 each own one
    // (s,r) value and issue one atomic
    #pragma unroll
    for (int off = 1; off < 16; off <<= 1)
        #pragma unroll
        for (int s = 0; s < 2; s++)
            #pragma unroll
            for (int r = 0; r < 4; r++)
                rs[s][r] += __shfl_xor(rs[s][r], off, 64);
    {
        float rv = 0.f;
        #pragma unroll
        for (int s = 0; s < 2; s++)
            #pragma unroll
            for (int r = 0; r < 4; r++)
                if (li == s * 4 + r) rv = rs[s][r];
        if (li < 8)
            atomicAdd(&ns8[d * B_N + r0 + (li >> 2) * 16 + q * 4 + (li & 3)], rv);
    }

    // col sums (mirrored tile coverage): cross-q reduce; each wave atomics its
    // own 32-row contribution (4 waves -> 4 atomics/column, negligible)
    if (!diag) {
        #pragma unroll
        for (int c = 0; c < 8; c++) {
            cs[c] += __shfl_xor(cs[c], 16, 64);
            cs[c] += __shfl_xor(cs[c], 32, 64);
        }
        float v0 = 0.f, v1 = 0.f;
        #pragma unroll
        for (int c = 0; c < 4; c++)
            if (q == c) { v0 = cs[c]; v1 = cs[c + 4]; }
        atomicAdd(&ns8[d * B_N + j * TILE + q * 16 + li], v0);
        atomicAdd(&ns8[d * B_N + j * TILE + 64 + q * 16 + li], v1);
    }
}

// ---------------------------------------------------------------------------
// Kernel 3: neg[b] = sum_d ns8[d][b] / (B-1); logits = pos/(pos+neg);
// loss = max + log(sum exp(l-max)) - mean(l). Shuffle-based reductions
// (correctness-verified in R8/R9/R10 passing runs; 2 syncthreads vs 24).
// ---------------------------------------------------------------------------
__global__ void final_kernel(const float* __restrict__ pos,
                             const float* __restrict__ ns8,
                             float* __restrict__ out) {
    __shared__ float redm[4], reds[4], redl[4];
    int t = threadIdx.x, w = t >> 6, lane = t & 63;
    float vals[8];
    float lmax = -1e30f;
    #pragma unroll
    for (int i = 0; i < 8; i++) {
        int idx = t * 8 + i;
        float nsum = 0.f;
        #pragma unroll
        for (int d = 0; d < D_V; d++) nsum += ns8[d * B_N + idx];
        float p = pos[idx];
        float l = p / (p + nsum * (1.0f / (float)(B_N - 1)));
        vals[i] = l;
        lmax = fmaxf(lmax, l);
    }
    lmax = wave_reduce_max(lmax);
    if (lane == 0) redm[w] = lmax;
    __syncthreads();
    float m = fmaxf(fmaxf(redm[0], redm[1]), fmaxf(redm[2], redm[3]));
    float se = 0.f, sl = 0.f;
    #pragma unroll
    for (int i = 0; i < 8; i++) { se += expf(vals[i] - m); sl += vals[i]; }
    se = wave_reduce_sum(se);
    sl = wave_reduce_sum(sl);
    if (lane == 0) { reds[w] = se; redl[w] = sl; }
    __syncthreads();
    if (t == 0) {
        float S = reds[0] + reds[1] + reds[2] + reds[3];
        float L = redl[0] + redl[1] + redl[2] + redl[3];
        out[0] = m + logf(S) - L * (1.0f / (float)B_N);
    }
}

extern "C" void kernel_launch(void* const* d_in, const int* in_sizes, int n_in,
                              void* d_out, int out_size, void* d_ws, size_t ws_size,
                              hipStream_t stream) {
    const float* z = (const float*)d_in[0];
    float* out = (float*)d_out;
    unsigned short* zn = (unsigned short*)d_ws;                        // 8 MB bf16 (pre-scaled)
    float* ns8 = (float*)((char*)d_ws + (size_t)D_V * B_N * F_D * 2);  // 64 KB
    float* pos = ns8 + D_V * B_N;                                      // 8 KB

    np_kernel<<<dim3(512), 256, 0, stream>>>(z, zn, ns8, pos);
    neg_kernel<<<dim3(136 * 8), 256, 0, stream>>>(zn, ns8);
    final_kernel<<<1, 256, 0, stream>>>(pos, ns8, out);
}